// Round 1
// baseline (979.933 us; speedup 1.0000x reference)
//
#include <hip/hip_runtime.h>
#include <math.h>

// Problem constants (from reference)
#define B_  32
#define T_  256
#define K_  16
#define F_  2048
#define NC_ 10

// Grid: 256 blocks = 4 F-quarter blocks per (side, batch-row).
//   side 0 = abnormal, side 1 = normal; q = F-quarter (128 float4 columns).
// Phase 1 (wave 0 of every block, redundant across the 4 q-blocks —
//   register/shfl-only, deterministic, tie-break lower idx == jax.lax.top_k):
//   exact top-K=16 of drop = fmagn*mask over T=256 via iterative argmax
//   extraction. Only q==0 lane 0 writes the sls mean -> vls_out.
// Phase 2 (all 128 threads): gather this block's F-quarter of the 16 selected
//   rows (float4, coalesced), mean over K, sum of squares, block-reduce ->
//   partial ss written to norm_part[bb*4+q]. finalize sums quarters + sqrt.
__global__ __launch_bounds__(128) void topk_gather_norm_kernel(
    const float* __restrict__ abnr_fmagn,
    const float* __restrict__ norm_fmagn,
    const float* __restrict__ abnr_feats,
    const float* __restrict__ norm_feats,
    const float* __restrict__ abnr_sls,
    const float* __restrict__ norm_sls,
    const float* __restrict__ drop_abn,
    const float* __restrict__ drop_norm,
    float* __restrict__ vls_out,     // [64]: [0..31]=abn, [32..63]=norm
    float* __restrict__ norm_part)   // [256]: partial ss, [bb*4+q]
{
    const int blk  = blockIdx.x;
    const int bb   = blk >> 2;       // (side,b): 0..63
    const int q    = blk & 3;        // F-quarter
    const int side = bb >> 5;
    const int b    = bb & 31;

    const float* fmagn = side ? norm_fmagn : abnr_fmagn;
    const float* dmask = side ? drop_norm  : drop_abn;
    const float* sls   = side ? norm_sls   : abnr_sls;
    // Only feats[-1] is used by the reference.
    const float* featb = (side ? norm_feats : abnr_feats)
                         + (size_t)(NC_ - 1) * B_ * T_ * F_
                         + (size_t)b * T_ * F_;

    __shared__ int   s_idx[K_];
    __shared__ float s_red[2];

    const int tid = threadIdx.x;

    if (tid < 64) {
        // lane holds elements t = 4*tid .. 4*tid+3
        const float4 v4 = ((const float4*)(fmagn + b * T_))[tid];
        const float4 m4 = ((const float4*)(dmask + b * T_))[tid];
        float v[4] = { v4.x * m4.x, v4.y * m4.y, v4.z * m4.z, v4.w * m4.w };
        float slsum = 0.f;
        for (int k = 0; k < K_; ++k) {
            float bv = v[0]; int bj = 0;
            if (v[1] > bv) { bv = v[1]; bj = 1; }
            if (v[2] > bv) { bv = v[2]; bj = 2; }
            if (v[3] > bv) { bv = v[3]; bj = 3; }
            int bi = tid * 4 + bj;
            // 64-lane butterfly argmax, tie-break smaller index
            for (int off = 32; off; off >>= 1) {
                float ov = __shfl_xor(bv, off);
                int   oi = __shfl_xor(bi, off);
                if (ov > bv || (ov == bv && oi < bi)) { bv = ov; bi = oi; }
            }
            // bi now wave-uniform; owner lane retires the winner
            if (tid == (bi >> 2)) v[bi & 3] = -1.0f;
            if (tid == 0) {
                s_idx[k] = bi;
                slsum += sls[b * T_ + bi];
            }
        }
        if (tid == 0 && q == 0) vls_out[side * B_ + b] = slsum * (1.0f / K_);
    }
    __syncthreads();

    // Phase 2: this block covers float4 columns [q*128 .. q*128+127]
    const int col = q * 128 + tid;
    float ax = 0.f, ay = 0.f, az = 0.f, aw = 0.f;
    #pragma unroll
    for (int k = 0; k < K_; ++k) {
        const float4* row = (const float4*)(featb + (size_t)s_idx[k] * F_);
        float4 r = row[col];
        ax += r.x; ay += r.y; az += r.z; aw += r.w;
    }
    const float inv = 1.0f / K_;
    ax *= inv; ay *= inv; az *= inv; aw *= inv;
    float ss = ax*ax + ay*ay + az*az + aw*aw;

    // 64-lane wave reduce, then across the 2 waves via LDS
    for (int off = 32; off; off >>= 1) ss += __shfl_xor(ss, off);
    const int lane = tid & 63;
    const int wave = tid >> 6;
    if (lane == 0) s_red[wave] = ss;
    __syncthreads();
    if (tid == 0) norm_part[bb * 4 + q] = s_red[0] + s_red[1];
}

// Final tiny reduction: 1 block, 64 threads (one per element of the 2B vector).
__global__ __launch_bounds__(64) void finalize_kernel(
    const float* __restrict__ vls,       // [64]: [0..31]=abn, [32..63]=norm
    const float* __restrict__ norm_part, // [256]: partial ss per (bb, quarter)
    const float* __restrict__ label,     // [64]
    float* __restrict__ out)             // [2]
{
    const int tid = threadIdx.x;

    // each lane owns bb = tid; assemble its L2 norm from the 4 partials
    float ssum = norm_part[tid * 4 + 0] + norm_part[tid * 4 + 1]
               + norm_part[tid * 4 + 2] + norm_part[tid * 4 + 3];
    float nrm = sqrtf(ssum);
    // lane tid<32 holds abnormal norms; partner lane tid+32 holds normal
    float other = __shfl_xor(nrm, 32);

    // reference order: vls = concat(vls_norm, vls_abn)
    float v   = (tid < 32) ? vls[32 + tid] : vls[tid - 32];
    float lab = label[tid];
    float logp   = fmaxf(logf(v),     -100.f);
    float log1mp = fmaxf(log1pf(-v),  -100.f);
    float bce = -(lab * logp + (1.f - lab) * log1mp);

    // loss_rtfm: halves are duplicated, so mean over 2B == mean over B
    float rt = 0.f;
    if (tid < 32) {
        float la = fabsf(100.f - nrm);   // abnormal row norm
        float ln = other;                // matching normal row norm
        float s = la + ln;
        rt = s * s;
    }
    for (int off = 32; off; off >>= 1) {
        bce += __shfl_xor(bce, off);
        rt  += __shfl_xor(rt,  off);
    }
    if (tid == 0) {
        out[0] = 1.0e-4f * (rt * (1.0f / 32.0f));   // ALPHA * loss_rtfm
        out[1] = bce * (1.0f / 64.0f);              // loss_bce
    }
}

extern "C" void kernel_launch(void* const* d_in, const int* in_sizes, int n_in,
                              void* d_out, int out_size, void* d_ws, size_t ws_size,
                              hipStream_t stream) {
    const float* abnr_fmagn = (const float*)d_in[0];
    const float* norm_fmagn = (const float*)d_in[1];
    const float* abnr_feats = (const float*)d_in[2];
    const float* norm_feats = (const float*)d_in[3];
    const float* abnr_sls   = (const float*)d_in[4];
    const float* norm_sls   = (const float*)d_in[5];
    const float* label      = (const float*)d_in[6];
    const float* drop_abn   = (const float*)d_in[7];
    const float* drop_norm  = (const float*)d_in[8];

    float* vls       = (float*)d_ws;        // 64 floats
    float* norm_part = vls + 64;            // 256 floats
    float* out       = (float*)d_out;       // 2 floats

    topk_gather_norm_kernel<<<256, 128, 0, stream>>>(
        abnr_fmagn, norm_fmagn, abnr_feats, norm_feats,
        abnr_sls, norm_sls, drop_abn, drop_norm, vls, norm_part);
    finalize_kernel<<<1, 64, 0, stream>>>(vls, norm_part, label, out);
}